// Round 12
// baseline (163.485 us; speedup 1.0000x reference)
//
#include <hip/hip_runtime.h>

#define NN   100000
#define NE   1600000
#define CIN  128
#define K2   256
#define COUT 128

typedef __attribute__((ext_vector_type(8))) short bf16x8;
typedef __attribute__((ext_vector_type(4))) float f32x4;

__device__ __forceinline__ ushort f2bf(float f) {
    union { float f; unsigned u; } v; v.f = f;
    unsigned r = (v.u + 0x7FFFu + ((v.u >> 16) & 1u)) >> 16;
    return (ushort)r;
}
__device__ __forceinline__ float bflo(unsigned p) {
    union { unsigned u; float f; } v; v.u = p << 16; return v.f;
}
__device__ __forceinline__ float bfhi(unsigned p) {
    union { unsigned u; float f; } v; v.u = p & 0xFFFF0000u; return v.f;
}

// ======================= V8: fused producer, deeper p3 pipeline =======================
// rec = src (bits 0..16) | (dst & 127) << 17 ; bin f = dst>>7 (782 bins of 128 nodes)

#define NBIN     784       // bins allocated (782 used)
#define CAP3     2304      // records per bin (mean 2041, +5.8 sigma)
#define LCAP     8         // LDS staging slots per bin
#define NB_BIN   512       // bin-role blocks
#define E_BIN    3125      // edges per bin block
#define SRCMASK  0x1FFFF
#define SCAP     1536      // per-half-bin src list cap

// ---- W f32 -> bf16 (blocks 0-31) + gctr zeroing (block 32) ----
__global__ __launch_bounds__(256) void k_castw(const float* __restrict__ w,
                                               ushort* __restrict__ wb,
                                               int* __restrict__ gctr) {
    int t = threadIdx.x;
    if (blockIdx.x < 32) {
        int i = blockIdx.x * 256 + t;
        float4 v = *reinterpret_cast<const float4*>(w + (size_t)i * 4);
        ushort4 r; r.x = f2bf(v.x); r.y = f2bf(v.y); r.z = f2bf(v.z); r.w = f2bf(v.w);
        *reinterpret_cast<ushort4*>(wb + (size_t)i * 4) = r;
    } else {
        for (int i = t; i < NBIN + 16; i += 256) gctr[i] = 0;
    }
}

// ---- FUSED: dual GEMM (784 blocks) || edge binning (512 blocks) ----
__global__ __launch_bounds__(256) void k_fuse(const float* __restrict__ x,
                                              const ushort* __restrict__ wb,
                                              const float* __restrict__ bias,
                                              const int* __restrict__ esrc,
                                              const int* __restrict__ edst,
                                              int* __restrict__ gctr,
                                              unsigned* __restrict__ gbin,
                                              ushort* __restrict__ yh,
                                              float* __restrict__ out) {
    __shared__ unsigned lbuf[NBIN * LCAP];    // 25 KB (bin role only)
    __shared__ int      lcnt[NBIN];
    __shared__ int      lbase[NBIN];

    int b = blockIdx.x, t = threadIdx.x;
    bool isGemm; int rb;
    if (b < 1024) { isGemm = ((b & 1) == 0); rb = b >> 1; }
    else          { isGemm = true;           rb = 512 + (b - 1024); }

    if (isGemm) {
        int wid = t >> 6, lane = t & 63;
        int lr = lane & 15, lk = lane >> 4;
        int row0 = rb * 128 + wid * 32;

        f32x4 acch[2][8], accx[2][8];
        #pragma unroll
        for (int m = 0; m < 2; ++m)
            #pragma unroll
            for (int n = 0; n < 8; ++n) { acch[m][n] = (f32x4)0.f; accx[m][n] = (f32x4)0.f; }

        #pragma unroll
        for (int kb = 0; kb < 4; ++kb) {
            int kofs = kb * 32 + lk * 8;
            bf16x8 a[2];
            #pragma unroll
            for (int m = 0; m < 2; ++m) {
                int r = row0 + m * 16 + lr; if (r >= NN) r = NN - 1;
                const float* xp = x + (size_t)r * CIN + kofs;
                float4 u0 = *reinterpret_cast<const float4*>(xp);
                float4 u1 = *reinterpret_cast<const float4*>(xp + 4);
                bf16x8 aa;
                aa[0] = (short)f2bf(u0.x); aa[1] = (short)f2bf(u0.y);
                aa[2] = (short)f2bf(u0.z); aa[3] = (short)f2bf(u0.w);
                aa[4] = (short)f2bf(u1.x); aa[5] = (short)f2bf(u1.y);
                aa[6] = (short)f2bf(u1.z); aa[7] = (short)f2bf(u1.w);
                a[m] = aa;
            }
            #pragma unroll
            for (int n = 0; n < 8; ++n) {
                const ushort* wrow = wb + (size_t)(n * 16 + lr) * K2 + kofs;
                bf16x8 bh = *reinterpret_cast<const bf16x8*>(wrow);        // Wh
                bf16x8 bx = *reinterpret_cast<const bf16x8*>(wrow + CIN);  // Wx
                acch[0][n] = __builtin_amdgcn_mfma_f32_16x16x32_bf16(a[0], bh, acch[0][n], 0, 0, 0);
                acch[1][n] = __builtin_amdgcn_mfma_f32_16x16x32_bf16(a[1], bh, acch[1][n], 0, 0, 0);
                accx[0][n] = __builtin_amdgcn_mfma_f32_16x16x32_bf16(a[0], bx, accx[0][n], 0, 0, 0);
                accx[1][n] = __builtin_amdgcn_mfma_f32_16x16x32_bf16(a[1], bx, accx[1][n], 0, 0, 0);
            }
        }

        float bv[8];
        #pragma unroll
        for (int n = 0; n < 8; ++n) bv[n] = bias[n * 16 + lr];

        #pragma unroll
        for (int m = 0; m < 2; ++m)
            #pragma unroll
            for (int j = 0; j < 4; ++j) {
                int r = row0 + m * 16 + lk * 4 + j;
                if (r < NN) {
                    #pragma unroll
                    for (int n = 0; n < 8; ++n) {
                        yh[(size_t)r * CIN + n * 16 + lr]   = f2bf(acch[m][n][j]);
                        out[(size_t)r * COUT + n * 16 + lr] = accx[m][n][j] + bv[n];
                    }
                }
            }
    } else {
        // ---- bin role ----
        for (int i = t; i < NBIN; i += 256) lcnt[i] = 0;
        __syncthreads();

        int base = rb * E_BIN;
        for (int e = t; e < E_BIN; e += 256) {
            int d = edst[base + e], s = esrc[base + e];
            int f = d >> 7;
            unsigned rec = (unsigned)s | ((unsigned)(d & 127) << 17);
            int p = atomicAdd(&lcnt[f], 1);
            if (p < LCAP) lbuf[(f << 3) + p] = rec;
            else {
                int gp = atomicAdd(&gctr[f], 1);
                if (gp < CAP3) gbin[(size_t)f * CAP3 + gp] = rec;
            }
        }
        __syncthreads();

        for (int f = t; f < NBIN; f += 256) {
            int n = lcnt[f]; if (n > LCAP) n = LCAP;
            lcnt[f] = n;
            lbase[f] = (n > 0) ? atomicAdd(&gctr[f], n) : 0;
        }
        __syncthreads();

        for (int s = t; s < NBIN * LCAP; s += 256) {
            int f = s >> 3, k = s & 7;
            if (k < lcnt[f]) {
                int g0 = lbase[f] + k;
                if (g0 < CAP3) gbin[(size_t)f * CAP3 + g0] = lbuf[s];
            }
        }
    }
}

// ---- p3: half-bin blocks (64 nodes), 2-pass global sort, 16-deep paired gather ----
__global__ __launch_bounds__(256) void k_p3(const int* __restrict__ gctr,
                                            const unsigned* __restrict__ gbin,
                                            const ushort* __restrict__ yh,
                                            float* __restrict__ out) {
    __shared__ int ssrc[SCAP];                // 6 KB
    __shared__ int hcnt[64];
    __shared__ int hbase[64];
    __shared__ int hcur[64];
    int f   = blockIdx.x >> 1;
    int sub = blockIdx.x & 1;
    int t = threadIdx.x;
    int wid = t >> 6, lane = t & 63;

    if (t < 64) hcnt[t] = 0;
    __syncthreads();

    int m = gctr[f]; if (m > CAP3) m = CAP3;
    const unsigned* recs = gbin + (size_t)f * CAP3;

    for (int i = t; i < m; i += 256) {
        unsigned r = recs[i];
        int node = (r >> 17) & 127;
        if ((node >> 6) == sub) atomicAdd(&hcnt[node & 63], 1);
    }
    __syncthreads();

    if (t < 64) {
        int v = hcnt[t];
        int s = v;
        #pragma unroll
        for (int d = 1; d < 64; d <<= 1) {
            int u = __shfl_up(s, d);
            if (lane >= d) s += u;
        }
        hbase[t] = s - v;
        hcur[t]  = s - v;
    }
    __syncthreads();

    for (int i = t; i < m; i += 256) {
        unsigned r = recs[i];
        int node = (r >> 17) & 127;
        if ((node >> 6) == sub) {
            int p = atomicAdd(&hcur[node & 63], 1);
            if (p < SCAP) ssrc[p] = (int)(r & SRCMASK);
        }
    }
    __syncthreads();

    // D: 16 nodes per wave; wave halves process 2 edges at once; 8 loads in flight
    int node0 = (f << 7) + (sub << 6);
    int half = lane >> 5;
    int chof = (lane & 31) * 4;
    for (int i = wid * 16; i < wid * 16 + 16; ++i) {
        int n = node0 + i;
        if (n >= NN) break;
        int d0 = hbase[i], dg = hcnt[i];
        float a0 = 0.f, a1 = 0.f, a2 = 0.f, a3 = 0.f;
        for (int e = 0; e < dg; e += 16) {
            #pragma unroll
            for (int q = 0; q < 8; ++q) {
                int idx = e + q * 2 + half;
                uint2 v = make_uint2(0u, 0u);
                if (idx < dg) {
                    int s = ssrc[d0 + idx];
                    v = *reinterpret_cast<const uint2*>(yh + ((size_t)s << 7) + chof);
                }
                a0 += bflo(v.x); a1 += bfhi(v.x);
                a2 += bflo(v.y); a3 += bfhi(v.y);
            }
        }
        a0 += __shfl(a0, lane ^ 32);
        a1 += __shfl(a1, lane ^ 32);
        a2 += __shfl(a2, lane ^ 32);
        a3 += __shfl(a3, lane ^ 32);
        float inv = (dg > 0) ? 1.0f / (float)dg : 0.0f;
        if (lane < 32) {
            f32x4* po = reinterpret_cast<f32x4*>(out + ((size_t)n << 7) + chof);
            f32x4 o = __builtin_nontemporal_load(po);
            o[0] += a0 * inv; o[1] += a1 * inv;
            o[2] += a2 * inv; o[3] += a3 * inv;
            __builtin_nontemporal_store(o, po);
        }
    }
}

// ======================= V2 fallback (round-5, validated) =======================

#define NXCD  8
#define PART  ((NN + NXCD - 1) / NXCD)
#define NB_SCAT  2048
#define NB_CAST  12500
#define NB_CASTW 32
#define CAP  64

__global__ __launch_bounds__(256) void k_fuse2(const float* __restrict__ x,
                                               const float* __restrict__ w,
                                               const int* __restrict__ src,
                                               const int* __restrict__ dst,
                                               int* __restrict__ cnt,
                                               int* __restrict__ csrF,
                                               ushort* hcat,
                                               ushort* __restrict__ wb) {
    int b = blockIdx.x, t = threadIdx.x;
    if (b < NB_SCAT) {
        int part = b & (NXCD - 1);
        int slot = b >> 3;
        int lo = part * PART;
        int hi = lo + PART; if (hi > NN) hi = NN;
        const int NCH = NE / 4;
        for (int c = slot * 256 + t; c < NCH; c += 256 * 256) {
            int4 d = *reinterpret_cast<const int4*>(dst + (size_t)c * 4);
            int4 s = *reinterpret_cast<const int4*>(src + (size_t)c * 4);
            if (d.x >= lo && d.x < hi) { int p = atomicAdd(&cnt[d.x], 1); csrF[(d.x << 6) + p] = s.x; }
            if (d.y >= lo && d.y < hi) { int p = atomicAdd(&cnt[d.y], 1); csrF[(d.y << 6) + p] = s.y; }
            if (d.z >= lo && d.z < hi) { int p = atomicAdd(&cnt[d.z], 1); csrF[(d.z << 6) + p] = s.z; }
            if (d.w >= lo && d.w < hi) { int p = atomicAdd(&cnt[d.w], 1); csrF[(d.w << 6) + p] = s.w; }
        }
    } else if (b < NB_SCAT + NB_CAST) {
        int i = (b - NB_SCAT) * 256 + t;
        int node = i >> 5, c4 = (i & 31) * 4;
        float4 v = *reinterpret_cast<const float4*>(x + (size_t)node * CIN + c4);
        ushort4 r; r.x = f2bf(v.x); r.y = f2bf(v.y); r.z = f2bf(v.z); r.w = f2bf(v.w);
        *reinterpret_cast<ushort4*>(hcat + (size_t)node * K2 + CIN + c4) = r;
    } else {
        int i = (b - NB_SCAT - NB_CAST) * 256 + t;
        float4 v = *reinterpret_cast<const float4*>(w + (size_t)i * 4);
        ushort4 r; r.x = f2bf(v.x); r.y = f2bf(v.y); r.z = f2bf(v.z); r.w = f2bf(v.w);
        *reinterpret_cast<ushort4*>(wb + (size_t)i * 4) = r;
    }
}

__global__ __launch_bounds__(256) void k_aggB(const int* __restrict__ cnt,
                                              const int* __restrict__ csrF,
                                              ushort* hcat) {
    int gw   = (blockIdx.x * 256 + threadIdx.x) >> 6;
    int lane = threadIdx.x & 63;
    if (gw >= NN) return;
    int gws = __builtin_amdgcn_readfirstlane(gw);
    int deg = cnt[gws];
    const int4* b4 = reinterpret_cast<const int4*>(csrF + ((size_t)gws << 6));
    int boff = CIN + lane * 2;
    float ax = 0.f, ay = 0.f;
    for (int e = 0; e < deg; e += 8) {
        int4 c0 = b4[(e >> 2)];
        int4 c1 = b4[(e >> 2) + 1];
        int ss[8] = {c0.x, c0.y, c0.z, c0.w, c1.x, c1.y, c1.z, c1.w};
        #pragma unroll
        for (int k = 0; k < 8; ++k) {
            bool ok = (e + k) < deg;
            int s = ok ? ss[k] : 0;
            unsigned v = *reinterpret_cast<const unsigned*>(hcat + ((size_t)s << 8) + boff);
            float mq = ok ? 1.f : 0.f;
            ax += mq * bflo(v); ay += mq * bfhi(v);
        }
    }
    float inv = (deg > 0) ? 1.0f / (float)deg : 0.0f;
    unsigned packed = (unsigned)f2bf(ax * inv) | ((unsigned)f2bf(ay * inv) << 16);
    *reinterpret_cast<unsigned*>(hcat + ((size_t)gw << 8) + lane * 2) = packed;
}

__global__ __launch_bounds__(256) void k_gemm(const ushort* hcat,
                                              const ushort* __restrict__ wb,
                                              const float* __restrict__ bias,
                                              float* out) {
    int t = threadIdx.x;
    int wid = t >> 6, lane = t & 63;
    int lr = lane & 15, lk = lane >> 4;
    int row0 = blockIdx.x * 128 + wid * 32;

    f32x4 acc[2][8];
    #pragma unroll
    for (int m = 0; m < 2; ++m)
        #pragma unroll
        for (int n = 0; n < 8; ++n) acc[m][n] = (f32x4)0.f;

    #pragma unroll
    for (int kb = 0; kb < 8; ++kb) {
        int kofs = kb * 32 + lk * 8;
        bf16x8 a[2];
        #pragma unroll
        for (int m = 0; m < 2; ++m) {
            int r = row0 + m * 16 + lr; if (r >= NN) r = NN - 1;
            a[m] = *reinterpret_cast<const bf16x8*>(hcat + ((size_t)r << 8) + kofs);
        }
        #pragma unroll
        for (int n = 0; n < 8; ++n) {
            bf16x8 bfr = *reinterpret_cast<const bf16x8*>(wb + (size_t)(n * 16 + lr) * K2 + kofs);
            acc[0][n] = __builtin_amdgcn_mfma_f32_16x16x32_bf16(a[0], bfr, acc[0][n], 0, 0, 0);
            acc[1][n] = __builtin_amdgcn_mfma_f32_16x16x32_bf16(a[1], bfr, acc[1][n], 0, 0, 0);
        }
    }

    float bv[8];
    #pragma unroll
    for (int n = 0; n < 8; ++n) bv[n] = bias[n * 16 + lr];

    #pragma unroll
    for (int m = 0; m < 2; ++m)
        #pragma unroll
        for (int j = 0; j < 4; ++j) {
            int r = row0 + m * 16 + lk * 4 + j;
            if (r < NN) {
                #pragma unroll
                for (int n = 0; n < 8; ++n)
                    out[(size_t)r * COUT + n * 16 + lr] = acc[m][n][j] + bv[n];
            }
        }
}

// ---------------- host ----------------

extern "C" void kernel_launch(void* const* d_in, const int* in_sizes, int n_in,
                              void* d_out, int out_size, void* d_ws, size_t ws_size,
                              hipStream_t stream) {
    (void)in_sizes; (void)n_in; (void)out_size;
    const float* x    = (const float*)d_in[0];
    const int*   esrc = (const int*)  d_in[1];
    const int*   edst = (const int*)  d_in[2];
    const float* wgt  = (const float*)d_in[3];
    const float* bias = (const float*)d_in[4];

    size_t ctr_ints  = 800;
    size_t bin_recs  = (size_t)NBIN * CAP3;
    size_t yh_elems  = (size_t)NN * CIN;
    size_t need_v8 = ctr_ints * 4 + bin_recs * 4
                   + yh_elems * 2 + (size_t)K2 * COUT * 2 + 256;

    if (ws_size >= need_v8) {
        int*      wsi  = (int*)d_ws;
        int*      gctr = wsi;
        unsigned* gbin = (unsigned*)(wsi + ctr_ints);
        ushort*   yh   = (ushort*)(gbin + bin_recs);
        ushort*   wb   = yh + yh_elems;
        float*    out  = (float*)d_out;

        k_castw<<<33, 256, 0, stream>>>(wgt, wb, gctr);
        k_fuse <<<1296, 256, 0, stream>>>(x, wb, bias, esrc, edst, gctr, gbin, yh, out);
        k_p3   <<<NBIN * 2, 256, 0, stream>>>(gctr, gbin, yh, out);
    } else {
        int* wsi  = (int*)d_ws;
        int* cnt  = wsi;
        int* csrF = wsi + NN;
        ushort* wb = (ushort*)(wsi + NN + (size_t)NN * CAP);
        ushort* hcat = (ushort*)d_out;

        hipMemsetAsync(cnt, 0, (size_t)NN * sizeof(int), stream);
        k_fuse2<<<NB_SCAT + NB_CAST + NB_CASTW, 256, 0, stream>>>(
            x, wgt, esrc, edst, cnt, csrF, hcat, wb);
        k_aggB <<<NN / 4, 256, 0, stream>>>(cnt, csrF, hcat);
        k_gemm <<<(NN + 127) / 128, 256, 0, stream>>>(hcat, wb, bias, (float*)d_out);
    }
}